// Round 1
// baseline (429.524 us; speedup 1.0000x reference)
//
#include <hip/hip_runtime.h>
#include <hip/hip_bf16.h>

#define N_NODES 50000
#define N_EDGES 800000
#define NODE_F 128
#define EDGE_F 16
#define HID 64
#define N_ACT 6
#define SCAN_B 256
#define NBLK_SCAN ((N_NODES + SCAN_B - 1) / SCAN_B) /* 196 */
#define CNT_PAD (NBLK_SCAN * SCAN_B)                /* 50176 */

#define RL(x, k) __uint_as_float(__builtin_amdgcn_readlane(__float_as_uint(x), (k)))

// ---------------- degree histogram ----------------
__global__ void k_deg(const int* __restrict__ ei, int* __restrict__ cnt) {
    int j = blockIdx.x * 256 + threadIdx.x;
    if (j < N_EDGES) atomicAdd(&cnt[ei[N_EDGES + j]], 1);
}

// ---------------- exclusive scan (3 kernels) ----------------
__global__ void k_scan1(const int* __restrict__ cnt, int* __restrict__ start,
                        int* __restrict__ parts) {
    __shared__ int sd[SCAN_B];
    int tid = threadIdx.x;
    int i = blockIdx.x * SCAN_B + tid;
    int v = (i < N_NODES) ? cnt[i] : 0;
    sd[tid] = v;
    __syncthreads();
    for (int off = 1; off < SCAN_B; off <<= 1) {
        int t = (tid >= off) ? sd[tid - off] : 0;
        __syncthreads();
        sd[tid] += t;
        __syncthreads();
    }
    start[i] = sd[tid] - v;                       // exclusive within block
    if (tid == SCAN_B - 1) parts[blockIdx.x] = sd[tid];
}

__global__ void k_scan2(int* __restrict__ parts) {
    __shared__ int sd[256];
    int tid = threadIdx.x;
    int v = (tid < NBLK_SCAN) ? parts[tid] : 0;
    sd[tid] = v;
    __syncthreads();
    for (int off = 1; off < 256; off <<= 1) {
        int t = (tid >= off) ? sd[tid - off] : 0;
        __syncthreads();
        sd[tid] += t;
        __syncthreads();
    }
    if (tid < NBLK_SCAN) parts[tid] = sd[tid] - v; // exclusive block offsets
}

__global__ void k_scan3(const int* __restrict__ cnt, int* __restrict__ start,
                        int* __restrict__ cursor, float* __restrict__ dinv,
                        const int* __restrict__ parts) {
    int i = blockIdx.x * SCAN_B + threadIdx.x;
    if (i >= N_NODES) return;
    int s = start[i] + parts[blockIdx.x];
    start[i] = s;
    cursor[i] = s;
    dinv[i] = rsqrtf((float)cnt[i] + 1.0f);       // self-loop adds 1
}

// ---------------- CSR fill: srcs grouped by dst ----------------
__global__ void k_fill(const int* __restrict__ ei, int* __restrict__ cursor,
                       int* __restrict__ srcs) {
    int j = blockIdx.x * 256 + threadIdx.x;
    if (j >= N_EDGES) return;
    int s = ei[j], d = ei[N_EDGES + j];
    int pos = atomicAdd(&cursor[d], 1);
    srcs[pos] = s;
}

// ---------------- node GEMM: hb[v][0..63] = dinv[v] * (node_x[v] @ Wn) ----------------
__launch_bounds__(256)
__global__ void k_gemm_n(const float* __restrict__ x, const float* __restrict__ Wn,
                         const float* __restrict__ dinv, float* __restrict__ hb) {
    const int lane = threadIdx.x & 63;
    const int wid = blockIdx.x * 4 + (threadIdx.x >> 6);
    const int nw = gridDim.x * 4;
    float w[NODE_F];
#pragma unroll
    for (int k = 0; k < NODE_F; ++k) w[k] = Wn[k * HID + lane];
    for (int v = wid; v < N_NODES; v += nw) {
        float x0 = x[v * NODE_F + lane];
        float x1 = x[v * NODE_F + 64 + lane];
        float a0 = 0.f, a1 = 0.f, a2 = 0.f, a3 = 0.f;
#pragma unroll
        for (int k = 0; k < 64; k += 4) {
            a0 = fmaf(RL(x0, k + 0), w[k + 0], a0);
            a1 = fmaf(RL(x0, k + 1), w[k + 1], a1);
            a2 = fmaf(RL(x0, k + 2), w[k + 2], a2);
            a3 = fmaf(RL(x0, k + 3), w[k + 3], a3);
        }
#pragma unroll
        for (int k = 0; k < 64; k += 4) {
            a0 = fmaf(RL(x1, k + 0), w[64 + k + 0], a0);
            a1 = fmaf(RL(x1, k + 1), w[64 + k + 1], a1);
            a2 = fmaf(RL(x1, k + 2), w[64 + k + 2], a2);
            a3 = fmaf(RL(x1, k + 3), w[64 + k + 3], a3);
        }
        hb[v * 128 + lane] = ((a0 + a1) + (a2 + a3)) * dinv[v];
    }
}

// ---------------- edge GEMM: head rows -> hb[v][64..127]; tail rows -> pe pool ----------------
__launch_bounds__(256)
__global__ void k_gemm_e(const float* __restrict__ ex, const float* __restrict__ We,
                         const float* __restrict__ dinv, const float* __restrict__ be,
                         float* __restrict__ hb, float* __restrict__ peS) {
    const int lane = threadIdx.x & 63;
    const int wib = threadIdx.x >> 6;
    const int wid = blockIdx.x * 4 + wib;
    const int nw = gridDim.x * 4;
    float w[EDGE_F];
#pragma unroll
    for (int k = 0; k < EDGE_F; ++k) w[k] = We[k * HID + lane];
    const float bel = be[lane];
    float pe = 0.f;
    for (int i = wid; i < N_EDGES; i += nw) {
        float xv = ex[i * EDGE_F + (lane & 15)];
        float a0 = 0.f, a1 = 0.f, a2 = 0.f, a3 = 0.f;
#pragma unroll
        for (int k = 0; k < 16; k += 4) {
            a0 = fmaf(RL(xv, k + 0), w[k + 0], a0);
            a1 = fmaf(RL(xv, k + 1), w[k + 1], a1);
            a2 = fmaf(RL(xv, k + 2), w[k + 2], a2);
            a3 = fmaf(RL(xv, k + 3), w[k + 3], a3);
        }
        float acc = (a0 + a1) + (a2 + a3);
        if (i < N_NODES) {
            hb[i * 128 + 64 + lane] = acc * dinv[i];
        } else {
            // deg==1 (self loop only): he[i] = relu(h_e[i] + be), goes straight to pool
            pe += fmaxf(acc + bel, 0.f);
        }
    }
    __shared__ float red[4][64];
    red[wib][lane] = pe;
    __syncthreads();
    if (wib == 0) {
        float t = red[0][lane] + red[1][lane] + red[2][lane] + red[3][lane];
        atomicAdd(&peS[(blockIdx.x & 7) * HID + lane], t);
    }
}

// ---------------- fused gather: both convs, relu, and pool in one pass ----------------
__launch_bounds__(256)
__global__ void k_gather(const int* __restrict__ start, const int* __restrict__ cnt,
                         const int* __restrict__ srcs, const float* __restrict__ dinv,
                         const float* __restrict__ hb, const float* __restrict__ bn,
                         const float* __restrict__ be, float* __restrict__ pnS,
                         float* __restrict__ peS) {
    const int lane = threadIdx.x & 63;
    const int wib = threadIdx.x >> 6;
    const int wid = blockIdx.x * 4 + wib;
    const int nw = gridDim.x * 4;
    const float bnl = bn[lane], bel = be[lane];
    float pn = 0.f, pe = 0.f;
    for (int v = wid; v < N_NODES; v += nw) {
        const int beg = start[v];
        const int end = beg + cnt[v];
        const float dv = dinv[v];
        float aN0 = hb[v * 128 + lane];        // self term (already * dinv[v])
        float aE0 = hb[v * 128 + 64 + lane];
        float aN1 = 0.f, aE1 = 0.f;
        int idx = beg;
        for (; idx + 1 < end; idx += 2) {
            int s0 = srcs[idx], s1 = srcs[idx + 1];
            aN0 += hb[s0 * 128 + lane];
            aE0 += hb[s0 * 128 + 64 + lane];
            aN1 += hb[s1 * 128 + lane];
            aE1 += hb[s1 * 128 + 64 + lane];
        }
        if (idx < end) {
            int s0 = srcs[idx];
            aN0 += hb[s0 * 128 + lane];
            aE0 += hb[s0 * 128 + 64 + lane];
        }
        pn += fmaxf(fmaf(dv, aN0 + aN1, bnl), 0.f);
        pe += fmaxf(fmaf(dv, aE0 + aE1, bel), 0.f);
    }
    __shared__ float redN[4][64];
    __shared__ float redE[4][64];
    redN[wib][lane] = pn;
    redE[wib][lane] = pe;
    __syncthreads();
    if (wib == 0) {
        float a = redN[0][lane] + redN[1][lane] + redN[2][lane] + redN[3][lane];
        float b = redE[0][lane] + redE[1][lane] + redE[2][lane] + redE[3][lane];
        atomicAdd(&pnS[(blockIdx.x & 7) * HID + lane], a);
        atomicAdd(&peS[(blockIdx.x & 7) * HID + lane], b);
    }
}

// ---------------- final: means -> FC (128x6) -> softmax -> out[6] ----------------
__global__ void k_final(const float* __restrict__ pnS, const float* __restrict__ peS,
                        const float* __restrict__ Wfc, const float* __restrict__ bfc,
                        float* __restrict__ out) {
    __shared__ float pool[128];
    __shared__ float logits[N_ACT];
    int t = threadIdx.x; // 128 threads
    float s = 0.f;
    if (t < 64) {
        for (int sh = 0; sh < 8; ++sh) s += pnS[sh * 64 + t];
        pool[t] = s * (1.0f / (float)N_NODES);
    } else {
        int l = t - 64;
        for (int sh = 0; sh < 8; ++sh) s += peS[sh * 64 + l];
        pool[t] = s * (1.0f / (float)N_EDGES);
    }
    __syncthreads();
    if (t < N_ACT) {
        float acc = bfc[t];
        for (int k = 0; k < 128; ++k) acc = fmaf(pool[k], Wfc[k * N_ACT + t], acc);
        logits[t] = acc;
    }
    __syncthreads();
    if (t < N_ACT) {
        float m = logits[0];
        for (int a = 1; a < N_ACT; ++a) m = fmaxf(m, logits[a]);
        float sum = 0.f;
        for (int a = 0; a < N_ACT; ++a) sum += expf(logits[a] - m);
        out[t] = expf(logits[t] - m) / sum;
    }
}

extern "C" void kernel_launch(void* const* d_in, const int* in_sizes, int n_in,
                              void* d_out, int out_size, void* d_ws, size_t ws_size,
                              hipStream_t stream) {
    (void)in_sizes; (void)n_in; (void)out_size; (void)ws_size;
    const float* node_x = (const float*)d_in[0];
    const int*   ei     = (const int*)d_in[1];   // [2, E] int32
    const float* edge_x = (const float*)d_in[2];
    const float* Wn     = (const float*)d_in[3];
    const float* bn     = (const float*)d_in[4];
    const float* We     = (const float*)d_in[5];
    const float* be     = (const float*)d_in[6];
    const float* Wfc    = (const float*)d_in[7];
    const float* bfc    = (const float*)d_in[8];
    float* out = (float*)d_out;                  // reference output dtype = float32

    // workspace layout (floats)
    float* ws    = (float*)d_ws;
    float* pnS   = ws;                         // 8 shards * 64
    float* peS   = ws + 8 * 64;                // 8 shards * 64
    int*   cnt   = (int*)(ws + 16 * 64);       // CNT_PAD
    int*   start = cnt + CNT_PAD;              // CNT_PAD
    int*   cursor= start + CNT_PAD;            // CNT_PAD
    int*   parts = cursor + CNT_PAD;           // 256
    float* dinv  = (float*)(parts + 256);      // CNT_PAD
    int*   srcs  = (int*)(dinv + CNT_PAD);     // N_EDGES
    float* hb    = (float*)(srcs + N_EDGES);   // N_NODES * 128  (node half | edge half)

    // zero: pool shards + degree counts
    hipMemsetAsync(d_ws, 0, (size_t)(16 * 64 + CNT_PAD) * 4, stream);

    k_deg  <<<(N_EDGES + 255) / 256, 256, 0, stream>>>(ei, cnt);
    k_scan1<<<NBLK_SCAN, SCAN_B, 0, stream>>>(cnt, start, parts);
    k_scan2<<<1, 256, 0, stream>>>(parts);
    k_scan3<<<NBLK_SCAN, SCAN_B, 0, stream>>>(cnt, start, cursor, dinv, parts);
    k_fill <<<(N_EDGES + 255) / 256, 256, 0, stream>>>(ei, cursor, srcs);
    k_gemm_n<<<512, 256, 0, stream>>>(node_x, Wn, dinv, hb);
    k_gemm_e<<<1024, 256, 0, stream>>>(edge_x, We, dinv, be, hb, peS);
    k_gather<<<1024, 256, 0, stream>>>(start, cnt, srcs, dinv, hb, bn, be, pnS, peS);
    k_final <<<1, 128, 0, stream>>>(pnS, peS, Wfc, bfc, out);
}

// Round 2
// 329.402 us; speedup vs baseline: 1.3039x; 1.3039x over previous
//
#include <hip/hip_runtime.h>
#include <hip/hip_bf16.h>

#define N_NODES 50000
#define N_EDGES 800000
#define NODE_F 128
#define EDGE_F 16
#define HID 64
#define N_ACT 6
#define SCAN_B 256
#define NBLK_SCAN ((N_NODES + SCAN_B - 1) / SCAN_B) /* 196 */
#define CNT_PAD (NBLK_SCAN * SCAN_B)                /* 50176 */

typedef __bf16 bf16x8 __attribute__((ext_vector_type(8)));
typedef float f32x4 __attribute__((ext_vector_type(4)));

__device__ __forceinline__ unsigned pk_bf16(float lo, float hi) {
    unsigned short a = __builtin_bit_cast(unsigned short, (__bf16)lo);
    unsigned short b = __builtin_bit_cast(unsigned short, (__bf16)hi);
    return (unsigned)a | ((unsigned)b << 16);
}
__device__ __forceinline__ float blo(unsigned u) { return __uint_as_float(u << 16); }
__device__ __forceinline__ float bhi(unsigned u) { return __uint_as_float(u & 0xffff0000u); }

// ---------------- degree histogram ----------------
__global__ void k_deg(const int* __restrict__ ei, int* __restrict__ cnt) {
    int j = blockIdx.x * 256 + threadIdx.x;
    if (j < N_EDGES) atomicAdd(&cnt[ei[N_EDGES + j]], 1);
}

// ---------------- exclusive scan (3 kernels) ----------------
__global__ void k_scan1(const int* __restrict__ cnt, int* __restrict__ start,
                        int* __restrict__ parts) {
    __shared__ int sd[SCAN_B];
    int tid = threadIdx.x;
    int i = blockIdx.x * SCAN_B + tid;
    int v = (i < N_NODES) ? cnt[i] : 0;
    sd[tid] = v;
    __syncthreads();
    for (int off = 1; off < SCAN_B; off <<= 1) {
        int t = (tid >= off) ? sd[tid - off] : 0;
        __syncthreads();
        sd[tid] += t;
        __syncthreads();
    }
    start[i] = sd[tid] - v;
    if (tid == SCAN_B - 1) parts[blockIdx.x] = sd[tid];
}

__global__ void k_scan2(int* __restrict__ parts) {
    __shared__ int sd[256];
    int tid = threadIdx.x;
    int v = (tid < NBLK_SCAN) ? parts[tid] : 0;
    sd[tid] = v;
    __syncthreads();
    for (int off = 1; off < 256; off <<= 1) {
        int t = (tid >= off) ? sd[tid - off] : 0;
        __syncthreads();
        sd[tid] += t;
        __syncthreads();
    }
    if (tid < NBLK_SCAN) parts[tid] = sd[tid] - v;
}

__global__ void k_scan3(const int* __restrict__ cnt, int* __restrict__ start,
                        int* __restrict__ cursor, float* __restrict__ dinv,
                        const int* __restrict__ parts) {
    int i = blockIdx.x * SCAN_B + threadIdx.x;
    if (i >= N_NODES) return;
    int s = start[i] + parts[blockIdx.x];
    start[i] = s;
    cursor[i] = s;
    dinv[i] = rsqrtf((float)cnt[i] + 1.0f);
}

// ---------------- CSR fill ----------------
__global__ void k_fill(const int* __restrict__ ei, int* __restrict__ cursor,
                       int* __restrict__ srcs) {
    int j = blockIdx.x * 256 + threadIdx.x;
    if (j >= N_EDGES) return;
    int s = ei[j], d = ei[N_EDGES + j];
    int pos = atomicAdd(&cursor[d], 1);
    srcs[pos] = s;
}

// ---------------- node GEMM (MFMA): hb[v] node half = bf16(dinv[v] * node_x[v] @ Wn) ----------------
// hb row layout (dwords, 64 per row): node pairs 0..31, edge pairs 32..63.
// pair p<16 packs cols (p, 16+p); p>=16 packs cols (16+p, 32+p).
__launch_bounds__(256)
__global__ void k_gemm_n(const float* __restrict__ x, const float* __restrict__ Wn,
                         const float* __restrict__ dinv, unsigned* __restrict__ hb) {
    const int lane = threadIdx.x & 63;
    const int g = lane >> 4, c = lane & 15;
    const int wid = blockIdx.x * 4 + (threadIdx.x >> 6);
    const int nw = gridDim.x * 4;

    bf16x8 bw[4][4]; // [kstep][ntile]
#pragma unroll
    for (int s = 0; s < 4; ++s)
#pragma unroll
        for (int t = 0; t < 4; ++t) {
#pragma unroll
            for (int j = 0; j < 8; ++j)
                bw[s][t][j] = (__bf16)Wn[(32 * s + 8 * g + j) * HID + t * 16 + c];
        }

    for (int tile = wid; tile < N_NODES / 16; tile += nw) {
        const int base = tile * 16;
        const int row = base + c;
        f32x4 acc0 = {}, acc1 = {}, acc2 = {}, acc3 = {};
#pragma unroll
        for (int s = 0; s < 4; ++s) {
            const float* p = x + (size_t)row * NODE_F + 32 * s + 8 * g;
            f32x4 v0 = *(const f32x4*)(p);
            f32x4 v1 = *(const f32x4*)(p + 4);
            bf16x8 a;
#pragma unroll
            for (int j = 0; j < 4; ++j) { a[j] = (__bf16)v0[j]; a[4 + j] = (__bf16)v1[j]; }
            acc0 = __builtin_amdgcn_mfma_f32_16x16x32_bf16(a, bw[s][0], acc0, 0, 0, 0);
            acc1 = __builtin_amdgcn_mfma_f32_16x16x32_bf16(a, bw[s][1], acc1, 0, 0, 0);
            acc2 = __builtin_amdgcn_mfma_f32_16x16x32_bf16(a, bw[s][2], acc2, 0, 0, 0);
            acc3 = __builtin_amdgcn_mfma_f32_16x16x32_bf16(a, bw[s][3], acc3, 0, 0, 0);
        }
#pragma unroll
        for (int q = 0; q < 4; ++q) {
            int i = base + 4 * g + q;
            float dv = dinv[i];
            hb[(size_t)i * 64 + c]      = pk_bf16(acc0[q] * dv, acc1[q] * dv);
            hb[(size_t)i * 64 + 16 + c] = pk_bf16(acc2[q] * dv, acc3[q] * dv);
        }
    }
}

// ---------------- edge GEMM (MFMA): head rows -> hb edge half; tail rows -> pool ----------------
__launch_bounds__(256)
__global__ void k_gemm_e(const float* __restrict__ ex, const float* __restrict__ We,
                         const float* __restrict__ dinv, const float* __restrict__ be,
                         unsigned* __restrict__ hb, float* __restrict__ poolS) {
    const int lane = threadIdx.x & 63;
    const int g = lane >> 4, c = lane & 15;
    const int wid = blockIdx.x * 4 + (threadIdx.x >> 6);
    const int nw = gridDim.x * 4;

    bf16x8 bw[4]; // [ntile], K=16 real, rest zero
#pragma unroll
    for (int t = 0; t < 4; ++t) {
        bw[t] = bf16x8{};
        if (g < 2) {
#pragma unroll
            for (int j = 0; j < 8; ++j)
                bw[t][j] = (__bf16)We[(8 * g + j) * HID + t * 16 + c];
        }
    }
    const float be0 = be[c], be1 = be[16 + c], be2 = be[32 + c], be3 = be[48 + c];
    float pe0 = 0.f, pe1 = 0.f, pe2 = 0.f, pe3 = 0.f;

    for (int tile = wid; tile < N_EDGES / 16; tile += nw) {
        const int base = tile * 16;
        bf16x8 a{};
        if (lane < 32) {
            const float* p = ex + (size_t)(base + c) * EDGE_F + 8 * g;
            f32x4 v0 = *(const f32x4*)(p);
            f32x4 v1 = *(const f32x4*)(p + 4);
#pragma unroll
            for (int j = 0; j < 4; ++j) { a[j] = (__bf16)v0[j]; a[4 + j] = (__bf16)v1[j]; }
        }
        f32x4 acc0 = {}, acc1 = {}, acc2 = {}, acc3 = {};
        acc0 = __builtin_amdgcn_mfma_f32_16x16x32_bf16(a, bw[0], acc0, 0, 0, 0);
        acc1 = __builtin_amdgcn_mfma_f32_16x16x32_bf16(a, bw[1], acc1, 0, 0, 0);
        acc2 = __builtin_amdgcn_mfma_f32_16x16x32_bf16(a, bw[2], acc2, 0, 0, 0);
        acc3 = __builtin_amdgcn_mfma_f32_16x16x32_bf16(a, bw[3], acc3, 0, 0, 0);

        if (base < N_NODES) { // whole tile < N_NODES (50000 % 16 == 0)
#pragma unroll
            for (int q = 0; q < 4; ++q) {
                int i = base + 4 * g + q;
                float dv = dinv[i];
                hb[(size_t)i * 64 + 32 + c] = pk_bf16(acc0[q] * dv, acc1[q] * dv);
                hb[(size_t)i * 64 + 48 + c] = pk_bf16(acc2[q] * dv, acc3[q] * dv);
            }
        } else { // tail: deg==1 self-loop only -> relu(h+be) straight to pool
#pragma unroll
            for (int q = 0; q < 4; ++q) {
                pe0 += fmaxf(acc0[q] + be0, 0.f);
                pe1 += fmaxf(acc1[q] + be1, 0.f);
                pe2 += fmaxf(acc2[q] + be2, 0.f);
                pe3 += fmaxf(acc3[q] + be3, 0.f);
            }
        }
    }
    // reduce over lane groups (bits 4,5)
#pragma unroll
    for (int off = 16; off < 64; off <<= 1) {
        pe0 += __shfl_xor(pe0, off);
        pe1 += __shfl_xor(pe1, off);
        pe2 += __shfl_xor(pe2, off);
        pe3 += __shfl_xor(pe3, off);
    }
    if (g == 0) {
        float* sh = poolS + (blockIdx.x & 7) * 128;
        atomicAdd(&sh[64 + 2 * c], pe0);      // pair c,    slot 0  (col c)
        atomicAdd(&sh[65 + 2 * c], pe1);      // pair c,    slot 1  (col 16+c)
        atomicAdd(&sh[96 + 2 * c], pe2);      // pair 16+c, slot 0  (col 32+c)
        atomicAdd(&sh[97 + 2 * c], pe3);      // pair 16+c, slot 1  (col 48+c)
    }
}

// ---------------- fused gather over bf16 hb: both convs + relu + pool ----------------
__launch_bounds__(256)
__global__ void k_gather(const int* __restrict__ start, const int* __restrict__ cnt,
                         const int* __restrict__ srcs, const float* __restrict__ dinv,
                         const unsigned* __restrict__ hb, const float* __restrict__ bn,
                         const float* __restrict__ be, float* __restrict__ poolS) {
    const int lane = threadIdx.x & 63;
    const int wib = threadIdx.x >> 6;
    const int wid = blockIdx.x * 4 + wib;
    const int nw = gridDim.x * 4;
    const int p = lane & 31;
    const int col0 = (p < 16) ? p : p + 16;
    const float* bias = (lane < 32) ? bn : be;
    const float b0 = bias[col0], b1 = bias[col0 + 16];
    float p0 = 0.f, p1 = 0.f;

    for (int v = wid; v < N_NODES; v += nw) {
        const int beg = start[v];
        const int end = beg + cnt[v];
        const float dv = dinv[v];
        unsigned u = hb[(size_t)v * 64 + lane]; // self term (already * dinv)
        float a0 = blo(u), a1 = bhi(u);
        float c0 = 0.f, c1 = 0.f;
        int idx = beg;
        for (; idx + 1 < end; idx += 2) {
            int s0 = srcs[idx], s1 = srcs[idx + 1];
            unsigned u0 = hb[(size_t)s0 * 64 + lane];
            unsigned u1 = hb[(size_t)s1 * 64 + lane];
            a0 += blo(u0); a1 += bhi(u0);
            c0 += blo(u1); c1 += bhi(u1);
        }
        if (idx < end) {
            int s0 = srcs[idx];
            unsigned u0 = hb[(size_t)s0 * 64 + lane];
            a0 += blo(u0); a1 += bhi(u0);
        }
        p0 += fmaxf(fmaf(dv, a0 + c0, b0), 0.f);
        p1 += fmaxf(fmaf(dv, a1 + c1, b1), 0.f);
    }
    __shared__ float red[4][128];
    red[wib][2 * lane] = p0;
    red[wib][2 * lane + 1] = p1;
    __syncthreads();
    if (wib == 0) {
        float* sh = poolS + (blockIdx.x & 7) * 128;
        int e0 = lane, e1 = lane + 64;
        float s0 = red[0][e0] + red[1][e0] + red[2][e0] + red[3][e0];
        float s1 = red[0][e1] + red[1][e1] + red[2][e1] + red[3][e1];
        atomicAdd(&sh[e0], s0);
        atomicAdd(&sh[e1], s1);
    }
}

// ---------------- final: unpermute + means -> FC -> softmax ----------------
__global__ void k_final(const float* __restrict__ poolS, const float* __restrict__ Wfc,
                        const float* __restrict__ bfc, float* __restrict__ out) {
    __shared__ float pool[128]; // unpermuted concat [node 64 | edge 64]
    __shared__ float logits[N_ACT];
    int t = threadIdx.x; // 128 threads
    float s = 0.f;
    for (int sh = 0; sh < 8; ++sh) s += poolS[sh * 128 + t];
    int half = t >> 6, r = t & 63, pp = r >> 1, slot = r & 1;
    int col = ((pp < 16) ? pp : pp + 16) + 16 * slot + 64 * half;
    pool[col] = s * (half ? (1.0f / (float)N_EDGES) : (1.0f / (float)N_NODES));
    __syncthreads();
    if (t < N_ACT) {
        float acc = bfc[t];
        for (int k = 0; k < 128; ++k) acc = fmaf(pool[k], Wfc[k * N_ACT + t], acc);
        logits[t] = acc;
    }
    __syncthreads();
    if (t < N_ACT) {
        float m = logits[0];
        for (int a = 1; a < N_ACT; ++a) m = fmaxf(m, logits[a]);
        float sum = 0.f;
        for (int a = 0; a < N_ACT; ++a) sum += expf(logits[a] - m);
        out[t] = expf(logits[t] - m) / sum;
    }
}

extern "C" void kernel_launch(void* const* d_in, const int* in_sizes, int n_in,
                              void* d_out, int out_size, void* d_ws, size_t ws_size,
                              hipStream_t stream) {
    (void)in_sizes; (void)n_in; (void)out_size; (void)ws_size;
    const float* node_x = (const float*)d_in[0];
    const int*   ei     = (const int*)d_in[1];
    const float* edge_x = (const float*)d_in[2];
    const float* Wn     = (const float*)d_in[3];
    const float* bn     = (const float*)d_in[4];
    const float* We     = (const float*)d_in[5];
    const float* be     = (const float*)d_in[6];
    const float* Wfc    = (const float*)d_in[7];
    const float* bfc    = (const float*)d_in[8];
    float* out = (float*)d_out;

    float* ws     = (float*)d_ws;
    float* poolS  = ws;                          // 8 * 128
    int*   cnt    = (int*)(ws + 8 * 128);        // CNT_PAD
    int*   start  = cnt + CNT_PAD;
    int*   cursor = start + CNT_PAD;
    int*   parts  = cursor + CNT_PAD;            // 256
    float* dinv   = (float*)(parts + 256);       // CNT_PAD
    int*   srcs   = (int*)(dinv + CNT_PAD);      // N_EDGES
    unsigned* hb  = (unsigned*)(srcs + N_EDGES); // N_NODES * 64 dwords (bf16 pairs)

    hipMemsetAsync(d_ws, 0, (size_t)(8 * 128 + CNT_PAD) * 4, stream);

    k_deg  <<<(N_EDGES + 255) / 256, 256, 0, stream>>>(ei, cnt);
    k_scan1<<<NBLK_SCAN, SCAN_B, 0, stream>>>(cnt, start, parts);
    k_scan2<<<1, 256, 0, stream>>>(parts);
    k_scan3<<<NBLK_SCAN, SCAN_B, 0, stream>>>(cnt, start, cursor, dinv, parts);
    k_fill <<<(N_EDGES + 255) / 256, 256, 0, stream>>>(ei, cursor, srcs);
    k_gemm_n<<<256, 256, 0, stream>>>(node_x, Wn, dinv, hb);
    k_gemm_e<<<1024, 256, 0, stream>>>(edge_x, We, dinv, be, hb, poolS);
    k_gather<<<1024, 256, 0, stream>>>(start, cnt, srcs, dinv, hb, bn, be, poolS);
    k_final <<<1, 128, 0, stream>>>(poolS, Wfc, bfc, out);
}

// Round 3
// 261.617 us; speedup vs baseline: 1.6418x; 1.2591x over previous
//
#include <hip/hip_runtime.h>
#include <hip/hip_bf16.h>

#define N_NODES 50000
#define N_EDGES 800000
#define NODE_F 128
#define EDGE_F 16
#define HID 64
#define N_ACT 6
#define NT_NODE (N_NODES / 16)   /* 3125 */
#define NT_EDGE (N_EDGES / 16)   /* 50000 */
#define SCAN_BLKS 196
#define CNT_PAD (SCAN_BLKS * 256) /* 50176 */

typedef __bf16 bf16x8 __attribute__((ext_vector_type(8)));
typedef float f32x4 __attribute__((ext_vector_type(4)));

static __device__ __forceinline__ unsigned pk_bf16(float lo, float hi) {
    unsigned short a = __builtin_bit_cast(unsigned short, (__bf16)lo);
    unsigned short b = __builtin_bit_cast(unsigned short, (__bf16)hi);
    return (unsigned)a | ((unsigned)b << 16);
}
static __device__ __forceinline__ float blo(unsigned u) { return __uint_as_float(u << 16); }
static __device__ __forceinline__ float bhi(unsigned u) { return __uint_as_float(u & 0xffff0000u); }

// ================= P0: edge-tail GEMM (pool-direct) || degree histogram =================
#define P0_GRID 960
#define P0_DEG0 832
__launch_bounds__(256)
__global__ void k_p0(const int* __restrict__ ei, const float* __restrict__ ex,
                     const float* __restrict__ We, const float* __restrict__ be,
                     int* __restrict__ cnt, float* __restrict__ poolS) {
    const int bid = blockIdx.x, tid = threadIdx.x;
    if (bid >= P0_DEG0) {
        const int nth = (P0_GRID - P0_DEG0) * 256;
        for (int j = (bid - P0_DEG0) * 256 + tid; j < N_EDGES; j += nth)
            atomicAdd(&cnt[ei[N_EDGES + j]], 1);
        return;
    }
    const int lane = tid & 63, wib = tid >> 6;
    const int g = lane >> 4, c = lane & 15;
    bf16x8 bw[4];
#pragma unroll
    for (int t = 0; t < 4; ++t) {
        bw[t] = bf16x8{};
        if (g < 2) {
#pragma unroll
            for (int j = 0; j < 8; ++j)
                bw[t][j] = (__bf16)We[(8 * g + j) * HID + t * 16 + c];
        }
    }
    const float be0 = be[c], be1 = be[16 + c], be2 = be[32 + c], be3 = be[48 + c];
    float pe0 = 0.f, pe1 = 0.f, pe2 = 0.f, pe3 = 0.f;
    const int wv = bid * 4 + wib, nw = P0_DEG0 * 4;
    for (int t = NT_NODE + wv; t < NT_EDGE; t += nw) {
        const int base = t * 16;
        bf16x8 a{};
        if (lane < 32) {
            const float* p = ex + (size_t)(base + c) * EDGE_F + 8 * g;
            f32x4 v0 = *(const f32x4*)(p);
            f32x4 v1 = *(const f32x4*)(p + 4);
#pragma unroll
            for (int j = 0; j < 4; ++j) { a[j] = (__bf16)v0[j]; a[4 + j] = (__bf16)v1[j]; }
        }
        f32x4 A0 = {}, A1 = {}, A2 = {}, A3 = {};
        A0 = __builtin_amdgcn_mfma_f32_16x16x32_bf16(a, bw[0], A0, 0, 0, 0);
        A1 = __builtin_amdgcn_mfma_f32_16x16x32_bf16(a, bw[1], A1, 0, 0, 0);
        A2 = __builtin_amdgcn_mfma_f32_16x16x32_bf16(a, bw[2], A2, 0, 0, 0);
        A3 = __builtin_amdgcn_mfma_f32_16x16x32_bf16(a, bw[3], A3, 0, 0, 0);
#pragma unroll
        for (int q = 0; q < 4; ++q) {
            pe0 += fmaxf(A0[q] + be0, 0.f);
            pe1 += fmaxf(A1[q] + be1, 0.f);
            pe2 += fmaxf(A2[q] + be2, 0.f);
            pe3 += fmaxf(A3[q] + be3, 0.f);
        }
    }
#pragma unroll
    for (int off = 16; off < 64; off <<= 1) {
        pe0 += __shfl_xor(pe0, off);
        pe1 += __shfl_xor(pe1, off);
        pe2 += __shfl_xor(pe2, off);
        pe3 += __shfl_xor(pe3, off);
    }
    if (g == 0) {
        float* sh = poolS + (bid & 7) * 128;
        atomicAdd(&sh[64 + 2 * c], pe0);
        atomicAdd(&sh[65 + 2 * c], pe1);
        atomicAdd(&sh[96 + 2 * c], pe2);
        atomicAdd(&sh[97 + 2 * c], pe3);
    }
}

// ================= P1: block scan + dinv =================
__global__ void k_p1(const int* __restrict__ cnt, int* __restrict__ start,
                     int* __restrict__ parts, float* __restrict__ dinv) {
    __shared__ int sd[256];
    const int tid = threadIdx.x, bid = blockIdx.x;
    const int i = bid * 256 + tid;
    const int v = (i < N_NODES) ? cnt[i] : 0;
    sd[tid] = v;
    __syncthreads();
    for (int off = 1; off < 256; off <<= 1) {
        int t = (tid >= off) ? sd[tid - off] : 0;
        __syncthreads();
        sd[tid] += t;
        __syncthreads();
    }
    start[i] = sd[tid] - v;
    if (tid == 255) parts[bid] = sd[tid];
    if (i < N_NODES) dinv[i] = rsqrtf((float)v + 1.0f);
}

// ================= P2: scan2 (block 0) || node GEMM || edge-head GEMM =================
#define P2_GRID 1024
#define P2_NODE_HI 783
__launch_bounds__(256)
__global__ void k_p2(const float* __restrict__ x, const float* __restrict__ Wn,
                     const float* __restrict__ ex, const float* __restrict__ We,
                     const float* __restrict__ dinv, int* __restrict__ parts,
                     unsigned* __restrict__ hb) {
    const int bid = blockIdx.x, tid = threadIdx.x;
    if (bid == 0) {
        __shared__ int sd[256];
        int v = (tid < SCAN_BLKS) ? parts[tid] : 0;
        sd[tid] = v;
        __syncthreads();
        for (int off = 1; off < 256; off <<= 1) {
            int t = (tid >= off) ? sd[tid - off] : 0;
            __syncthreads();
            sd[tid] += t;
            __syncthreads();
        }
        if (tid < SCAN_BLKS) parts[tid] = sd[tid] - v;
        return;
    }
    const int lane = tid & 63, wib = tid >> 6;
    const int g = lane >> 4, c = lane & 15;
    if (bid < P2_NODE_HI) {
        // ---- node GEMM: hb[v] dwords 0..31 = bf16(dinv[v] * node_x[v] @ Wn) ----
        bf16x8 bw[4][4];
#pragma unroll
        for (int s = 0; s < 4; ++s)
#pragma unroll
            for (int t = 0; t < 4; ++t) {
#pragma unroll
                for (int j = 0; j < 8; ++j)
                    bw[s][t][j] = (__bf16)Wn[(32 * s + 8 * g + j) * HID + t * 16 + c];
            }
        const int wv = (bid - 1) * 4 + wib, nw = (P2_NODE_HI - 1) * 4;
        for (int tile = wv; tile < NT_NODE; tile += nw) {
            const int base = tile * 16;
            const int row = base + c;
            f32x4 acc0 = {}, acc1 = {}, acc2 = {}, acc3 = {};
#pragma unroll
            for (int s = 0; s < 4; ++s) {
                const float* p = x + (size_t)row * NODE_F + 32 * s + 8 * g;
                f32x4 v0 = *(const f32x4*)(p);
                f32x4 v1 = *(const f32x4*)(p + 4);
                bf16x8 a;
#pragma unroll
                for (int j = 0; j < 4; ++j) { a[j] = (__bf16)v0[j]; a[4 + j] = (__bf16)v1[j]; }
                acc0 = __builtin_amdgcn_mfma_f32_16x16x32_bf16(a, bw[s][0], acc0, 0, 0, 0);
                acc1 = __builtin_amdgcn_mfma_f32_16x16x32_bf16(a, bw[s][1], acc1, 0, 0, 0);
                acc2 = __builtin_amdgcn_mfma_f32_16x16x32_bf16(a, bw[s][2], acc2, 0, 0, 0);
                acc3 = __builtin_amdgcn_mfma_f32_16x16x32_bf16(a, bw[s][3], acc3, 0, 0, 0);
            }
#pragma unroll
            for (int q = 0; q < 4; ++q) {
                int i = base + 4 * g + q;
                float dv = dinv[i];
                hb[(size_t)i * 64 + c]      = pk_bf16(acc0[q] * dv, acc1[q] * dv);
                hb[(size_t)i * 64 + 16 + c] = pk_bf16(acc2[q] * dv, acc3[q] * dv);
            }
        }
    } else {
        // ---- edge-head GEMM: rows < N_NODES -> hb dwords 32..63 ----
        bf16x8 bw[4];
#pragma unroll
        for (int t = 0; t < 4; ++t) {
            bw[t] = bf16x8{};
            if (g < 2) {
#pragma unroll
                for (int j = 0; j < 8; ++j)
                    bw[t][j] = (__bf16)We[(8 * g + j) * HID + t * 16 + c];
            }
        }
        const int wv = (bid - P2_NODE_HI) * 4 + wib, nw = (P2_GRID - P2_NODE_HI) * 4;
        for (int tile = wv; tile < NT_NODE; tile += nw) {
            const int base = tile * 16;
            bf16x8 a{};
            if (lane < 32) {
                const float* p = ex + (size_t)(base + c) * EDGE_F + 8 * g;
                f32x4 v0 = *(const f32x4*)(p);
                f32x4 v1 = *(const f32x4*)(p + 4);
#pragma unroll
                for (int j = 0; j < 4; ++j) { a[j] = (__bf16)v0[j]; a[4 + j] = (__bf16)v1[j]; }
            }
            f32x4 A0 = {}, A1 = {}, A2 = {}, A3 = {};
            A0 = __builtin_amdgcn_mfma_f32_16x16x32_bf16(a, bw[0], A0, 0, 0, 0);
            A1 = __builtin_amdgcn_mfma_f32_16x16x32_bf16(a, bw[1], A1, 0, 0, 0);
            A2 = __builtin_amdgcn_mfma_f32_16x16x32_bf16(a, bw[2], A2, 0, 0, 0);
            A3 = __builtin_amdgcn_mfma_f32_16x16x32_bf16(a, bw[3], A3, 0, 0, 0);
#pragma unroll
            for (int q = 0; q < 4; ++q) {
                int i = base + 4 * g + q;
                float dv = dinv[i];
                hb[(size_t)i * 64 + 32 + c] = pk_bf16(A0[q] * dv, A1[q] * dv);
                hb[(size_t)i * 64 + 48 + c] = pk_bf16(A2[q] * dv, A3[q] * dv);
            }
        }
    }
}

// ================= P3: apply scanned offsets =================
__global__ void k_p3(const int* __restrict__ parts, int* __restrict__ start,
                     int* __restrict__ cursor) {
    const int i = blockIdx.x * 256 + threadIdx.x;
    if (i >= N_NODES) return;
    const int s = start[i] + parts[blockIdx.x];
    start[i] = s;
    cursor[i] = s;
}

// ================= P4: CSR fill =================
#define P4_GRID 2048
__global__ void k_p4(const int* __restrict__ ei, int* __restrict__ cursor,
                     int* __restrict__ srcs) {
    for (int j = blockIdx.x * 256 + threadIdx.x; j < N_EDGES; j += P4_GRID * 256) {
        const int s = ei[j], d = ei[N_EDGES + j];
        const int pos = atomicAdd(&cursor[d], 1);
        srcs[pos] = s;
    }
}

// ================= P5: fused gather (both convs) + relu + pool =================
#define P5_GRID 2048
__launch_bounds__(256)
__global__ void k_p5(const int* __restrict__ start, const int* __restrict__ cnt,
                     const int* __restrict__ srcs, const float* __restrict__ dinv,
                     const unsigned* __restrict__ hb, const float* __restrict__ bn,
                     const float* __restrict__ be, float* __restrict__ poolS) {
    const int tid = threadIdx.x;
    const int lane = tid & 63, wib = tid >> 6;
    const int p = lane & 31;
    const int col0 = (p < 16) ? p : p + 16;
    const float* bias = (lane < 32) ? bn : be;
    const float b0 = bias[col0], b1 = bias[col0 + 16];
    float p0 = 0.f, p1 = 0.f;
    const int wv = blockIdx.x * 4 + wib, nw = P5_GRID * 4;
    for (int v = wv; v < N_NODES; v += nw) {
        const int beg = start[v];
        const int dg = cnt[v];
        const float dv = dinv[v];
        const unsigned us = hb[(size_t)v * 64 + lane]; // self term (already * dinv)
        float a0 = blo(us), a1 = bhi(us);
        float c0 = 0.f, c1 = 0.f, d0 = 0.f, d1 = 0.f, e0 = 0.f, e1 = 0.f;
        float f0 = 0.f, f1 = 0.f, g0 = 0.f, g1 = 0.f, h0 = 0.f, h1 = 0.f;
        float m0 = 0.f, m1 = 0.f, z0 = 0.f, z1 = 0.f;
        for (int bb = 0; bb < dg; bb += 64) {
            int rem = dg - bb;
            rem = (rem > 64) ? 64 : rem;
            const int sv = (lane < rem) ? srcs[beg + bb + lane] : 0;
            int k = 0;
            for (; k + 7 < rem; k += 8) {
                const int i0 = __builtin_amdgcn_readlane(sv, k);
                const int i1 = __builtin_amdgcn_readlane(sv, k + 1);
                const int i2 = __builtin_amdgcn_readlane(sv, k + 2);
                const int i3 = __builtin_amdgcn_readlane(sv, k + 3);
                const int i4 = __builtin_amdgcn_readlane(sv, k + 4);
                const int i5 = __builtin_amdgcn_readlane(sv, k + 5);
                const int i6 = __builtin_amdgcn_readlane(sv, k + 6);
                const int i7 = __builtin_amdgcn_readlane(sv, k + 7);
                const unsigned u0 = hb[(size_t)i0 * 64 + lane];
                const unsigned u1 = hb[(size_t)i1 * 64 + lane];
                const unsigned u2 = hb[(size_t)i2 * 64 + lane];
                const unsigned u3 = hb[(size_t)i3 * 64 + lane];
                const unsigned u4 = hb[(size_t)i4 * 64 + lane];
                const unsigned u5 = hb[(size_t)i5 * 64 + lane];
                const unsigned u6 = hb[(size_t)i6 * 64 + lane];
                const unsigned u7 = hb[(size_t)i7 * 64 + lane];
                a0 += blo(u0); a1 += bhi(u0);
                c0 += blo(u1); c1 += bhi(u1);
                d0 += blo(u2); d1 += bhi(u2);
                e0 += blo(u3); e1 += bhi(u3);
                f0 += blo(u4); f1 += bhi(u4);
                g0 += blo(u5); g1 += bhi(u5);
                h0 += blo(u6); h1 += bhi(u6);
                m0 += blo(u7); m1 += bhi(u7);
            }
            for (; k < rem; ++k) {
                const int i0 = __builtin_amdgcn_readlane(sv, k);
                const unsigned u0 = hb[(size_t)i0 * 64 + lane];
                z0 += blo(u0); z1 += bhi(u0);
            }
        }
        const float S0 = (((a0 + c0) + (d0 + e0)) + ((f0 + g0) + (h0 + m0))) + z0;
        const float S1 = (((a1 + c1) + (d1 + e1)) + ((f1 + g1) + (h1 + m1))) + z1;
        p0 += fmaxf(fmaf(dv, S0, b0), 0.f);
        p1 += fmaxf(fmaf(dv, S1, b1), 0.f);
    }
    __shared__ float red[4][128];
    red[wib][2 * lane] = p0;
    red[wib][2 * lane + 1] = p1;
    __syncthreads();
    if (wib == 0) {
        float* sh = poolS + (blockIdx.x & 7) * 128;
        const float s0 = red[0][lane] + red[1][lane] + red[2][lane] + red[3][lane];
        const float s1 = red[0][lane + 64] + red[1][lane + 64] + red[2][lane + 64] + red[3][lane + 64];
        atomicAdd(&sh[lane], s0);
        atomicAdd(&sh[lane + 64], s1);
    }
}

// ================= P6: unpermute + means -> FC -> softmax =================
__global__ void k_p6(const float* __restrict__ poolS, const float* __restrict__ Wfc,
                     const float* __restrict__ bfc, float* __restrict__ out) {
    __shared__ float pool[128];
    __shared__ float logits[N_ACT];
    const int t = threadIdx.x; // 128 threads
    float s = 0.f;
    for (int sh = 0; sh < 8; ++sh) s += poolS[sh * 128 + t];
    const int half = t >> 6, r = t & 63, pp = r >> 1, slot = r & 1;
    const int col = ((pp < 16) ? pp : pp + 16) + 16 * slot + 64 * half;
    pool[col] = s * (half ? (1.0f / (float)N_EDGES) : (1.0f / (float)N_NODES));
    __syncthreads();
    if (t < N_ACT) {
        float acc = bfc[t];
        for (int k = 0; k < 128; ++k) acc = fmaf(pool[k], Wfc[k * N_ACT + t], acc);
        logits[t] = acc;
    }
    __syncthreads();
    if (t < N_ACT) {
        float m = logits[0];
        for (int a = 1; a < N_ACT; ++a) m = fmaxf(m, logits[a]);
        float sum = 0.f;
        for (int a = 0; a < N_ACT; ++a) sum += expf(logits[a] - m);
        out[t] = expf(logits[t] - m) / sum;
    }
}

extern "C" void kernel_launch(void* const* d_in, const int* in_sizes, int n_in,
                              void* d_out, int out_size, void* d_ws, size_t ws_size,
                              hipStream_t stream) {
    (void)in_sizes; (void)n_in; (void)out_size; (void)ws_size;
    const float* node_x = (const float*)d_in[0];
    const int*   ei     = (const int*)d_in[1];
    const float* edge_x = (const float*)d_in[2];
    const float* Wn     = (const float*)d_in[3];
    const float* bn     = (const float*)d_in[4];
    const float* We     = (const float*)d_in[5];
    const float* be     = (const float*)d_in[6];
    const float* Wfc    = (const float*)d_in[7];
    const float* bfc    = (const float*)d_in[8];
    float* out = (float*)d_out;

    float* ws     = (float*)d_ws;
    float* poolS  = ws;                          // 8 * 128
    int*   cnt    = (int*)(ws + 8 * 128);        // CNT_PAD
    int*   start  = cnt + CNT_PAD;               // CNT_PAD
    int*   cursor = start + CNT_PAD;             // CNT_PAD
    int*   parts  = cursor + CNT_PAD;            // 256
    float* dinv   = (float*)(parts + 256);       // CNT_PAD
    int*   srcs   = (int*)(dinv + CNT_PAD);      // N_EDGES
    unsigned* hb  = (unsigned*)(srcs + N_EDGES); // N_NODES * 64 dwords (bf16 pairs)

    hipMemsetAsync(d_ws, 0, (size_t)(8 * 128 + CNT_PAD) * 4, stream);

    k_p0<<<P0_GRID, 256, 0, stream>>>(ei, edge_x, We, be, cnt, poolS);
    k_p1<<<SCAN_BLKS, 256, 0, stream>>>(cnt, start, parts, dinv);
    k_p2<<<P2_GRID, 256, 0, stream>>>(node_x, Wn, edge_x, We, dinv, parts, hb);
    k_p3<<<SCAN_BLKS, 256, 0, stream>>>(parts, start, cursor);
    k_p4<<<P4_GRID, 256, 0, stream>>>(ei, cursor, srcs);
    k_p5<<<P5_GRID, 256, 0, stream>>>(start, cnt, srcs, dinv, hb, bn, be, poolS);
    k_p6<<<1, 128, 0, stream>>>(poolS, Wfc, bfc, out);
}